// Round 12
// baseline (81.969 us; speedup 1.0000x reference)
//
#include <hip/hip_runtime.h>
#include <hip/hip_bf16.h>
#include <cstddef>
#include <cstdint>

#define N_ST 256
#define TWO_N 512
#define NU 128
#define BATCH 16
#define TSTEPS 2048
#define MTOT (BATCH * TSTEPS)   // 32768
#define H_STEP 0.01f
#define EPS_V 0.001f
#define NCHUNK 32
#define CHUNKL 64

typedef __attribute__((ext_vector_type(4))) float f32x4;
typedef __attribute__((ext_vector_type(4))) short s16x4;
typedef __attribute__((ext_vector_type(8))) short s16x8;

// ---- workspace layout (float offsets) ----
#define OFF_FPK    0            // 16777216 shorts: packed bf16 F [(m>>4)][k=512][m&15]
#define OFF_ZPK    8388608      // 16777216 shorts: packed bf16 Z, same layout
#define OFF_UPK    16777216     // 4194304 shorts: packed bf16 u [(m>>4)][k=128][m&15]
#define OFF_WT     18874368     // 262144 shorts
#define OFF_WF     19005440     // 65536 shorts
#define OFF_D      19038208     // 1024 f32
#define OFF_XBAR0  19039232     // 8192 f32
#define OFF_E      19047424     // 512*512 f32

static __device__ __forceinline__ float bf2f(short s) {
    return __uint_as_float(((unsigned)(unsigned short)s) << 16);
}

// ---- fused precompute: blocks 0..1023 prep_W, 1024..1279 prep_Wf, 1280 prep_d
__global__ __launch_bounds__(256) void prep_all(
    const float* __restrict__ P_re, const float* __restrict__ P_im,
    const float* __restrict__ B_re, const float* __restrict__ B_im,
    const float* __restrict__ alpha, const float* __restrict__ theta,
    short* __restrict__ Wtpk, short* __restrict__ Wfpk,
    float* __restrict__ dbuf)
{
    int blk = blockIdx.x, tid = threadIdx.x;
    if (blk < 1024) {
        int idx = blk * 256 + tid;
        int j = idx >> 9, c = idx & 511;
        float v;
        if (c < N_ST) v = P_re[j * TWO_N + c] + P_re[j * TWO_N + c + N_ST];
        else          v = P_im[j * TWO_N + c] - P_im[j * TWO_N + c - N_ST];
        __hip_bfloat16 b = __float2bfloat16(v);
        Wtpk[((size_t)(j >> 4) * TWO_N + c) * 16 + (j & 15)] = *(short*)&b;
    } else if (blk < 1280) {
        int idx = (blk - 1024) * 256 + tid;
        int k = idx >> 9, c = idx & 511;
        float v = (c < N_ST) ? B_re[c * NU + k] : B_im[(c - N_ST) * NU + k];
        __hip_bfloat16 b = __float2bfloat16(H_STEP * v);
        Wfpk[((size_t)(c >> 4) * NU + k) * 16 + (c & 15)] = *(short*)&b;
    } else {
        int i = tid;
        float dr = 1.0f + H_STEP * (-expf(alpha[i]) - EPS_V);
        float di = H_STEP * theta[i];
        float pr = 1.0f, pi = 0.0f;
        for (int k = 0; k < CHUNKL; ++k) { float nr = pr * dr - pi * di; pi = pr * di + pi * dr; pr = nr; }
        dbuf[i] = dr; dbuf[N_ST + i] = di; dbuf[2 * N_ST + i] = pr; dbuf[3 * N_ST + i] = pi;
    }
}

// ---- xbar0: coalesced, wave-per-state. 64 blocks x 256 thr; wave w -> state i.
__global__ __launch_bounds__(256) void xbar0_kernel(
    const float* __restrict__ Pinv_re, const float* __restrict__ Pinv_im,
    const float* __restrict__ xi0, float* __restrict__ xbar0)
{
    __shared__ float xs[BATCH * TWO_N];   // 32 KB
    int tid = threadIdx.x;
#pragma unroll
    for (int q = 0; q < 8; ++q)
        *reinterpret_cast<float4*>(&xs[(q * 256 + tid) * 4]) =
            *reinterpret_cast<const float4*>(&xi0[(q * 256 + tid) * 4]);
    __syncthreads();

    int wv = tid >> 6, l = tid & 63;
    int i = blockIdx.x * 4 + wv;          // state 0..255
    float rp[BATCH] = {}, ip[BATCH] = {};
#pragma unroll
    for (int q = 0; q < 8; ++q) {
        int j = q * 64 + l;
        float pr = Pinv_re[(size_t)i * TWO_N + j];
        float pi = Pinv_im[(size_t)i * TWO_N + j];
#pragma unroll
        for (int b = 0; b < BATCH; ++b) {
            float x = xs[b * TWO_N + j];
            rp[b] = fmaf(pr, x, rp[b]);
            ip[b] = fmaf(pi, x, ip[b]);
        }
    }
#pragma unroll
    for (int m = 1; m < 64; m <<= 1) {
#pragma unroll
        for (int b = 0; b < BATCH; ++b) {
            rp[b] += __shfl_xor(rp[b], m, 64);
            ip[b] += __shfl_xor(ip[b], m, 64);
        }
    }
    if (l == 0) {
#pragma unroll
        for (int b = 0; b < BATCH; ++b) {
            xbar0[b * TWO_N + i] = rp[b];
            xbar0[b * TWO_N + N_ST + i] = ip[b];
        }
    }
}

// coalesced u -> packed bf16 via LDS transpose
__global__ __launch_bounds__(256) void upack(const float* __restrict__ u, short* __restrict__ upk) {
    __shared__ short st[64 * 132];
    int tid = threadIdx.x, bid = blockIdx.x;   // 512 blocks: 64 m x 128 k each
    const float* up = u + (size_t)bid * 8192;
#pragma unroll
    for (int q = 0; q < 8; ++q) {
        int idx = q * 1024 + tid * 4;
        float4 v = *reinterpret_cast<const float4*>(up + idx);
        int m = idx >> 7, k = idx & 127;
        s16x4 pv;
        __hip_bfloat16 b0 = __float2bfloat16(v.x); pv[0] = *(short*)&b0;
        __hip_bfloat16 b1 = __float2bfloat16(v.y); pv[1] = *(short*)&b1;
        __hip_bfloat16 b2 = __float2bfloat16(v.z); pv[2] = *(short*)&b2;
        __hip_bfloat16 b3 = __float2bfloat16(v.w); pv[3] = *(short*)&b3;
        *reinterpret_cast<__shared__ s16x4*>(&st[m * 132 + k]) = pv;
    }
    __syncthreads();
    short* op = upk + (size_t)bid * 8192;
#pragma unroll
    for (int q2 = 0; q2 < 4; ++q2) {
        int o = q2 * 2048 + tid * 8;
        int ml = o & 15, k = (o >> 4) & 127, sl = o >> 11;
        s16x8 w;
#pragma unroll
        for (int r = 0; r < 8; ++r) w[r] = st[(sl * 16 + ml + r) * 132 + k];
        *reinterpret_cast<s16x8*>(op + o) = w;
    }
}

// ---- bf16 MFMA GEMM, 256x256 tile, 8 waves, 2-buf ring, 4 fine phases per
// K-step (m201-style T3+T4+T5): per phase {1 stage-load issue, small tr_read
// cluster, lgkmcnt(0), 8 MFMA (setprio-wrapped), raw barrier}. vmcnt counted
// once per K-step (phase 0), never drained to 0 in the main loop.
template <int K, bool PACKOUT>
__global__ __launch_bounds__(512, 2) void gemm_mfma(const short* __restrict__ Apk,
                                                    const short* __restrict__ Bpk,
                                                    float* __restrict__ Cf,
                                                    short* __restrict__ Cp,
                                                    const float* __restrict__ xi0) {
    __shared__ __align__(1024) short lds[32768];   // A: buf*8192, B: 16384 + buf*8192
    const int tid = threadIdx.x;
    const int wid = tid >> 6, lane = tid & 63;
    const int l = blockIdx.x;
    const int mb = ((l >> 4) << 3) | (l & 7);      // XCD-pairing swizzle
    const int nb = (l >> 3) & 1;
    const int m0 = mb * 256, n0 = nb * 256;
    const int wm = wid >> 2, wn = wid & 3;         // 2 x 4 wave grid; wave tile 128x64
    f32x4 acc[8][4] = {};
    const size_t slabStride = (size_t)K * 16;
    const unsigned ldsBase = (unsigned)(uintptr_t)(__attribute__((address_space(3))) short*)&lds[0];
    constexpr int NT = K / 32;

    // one stage-load per phase p: p0 -> A row wid, p1 -> A row wid+8,
    // p2 -> B row wid, p3 -> B row wid+8
#define STAGE1(buf, kk, p)                                                                          \
    do {                                                                                            \
        const bool isA_ = (p) < 2;                                                                  \
        const int r_ = ((p) & 1) ? wid + 8 : wid;                                                   \
        const short* src_ = (isA_ ? Apk + ((size_t)(m0 >> 4) + r_) * slabStride                     \
                                  : Bpk + ((size_t)(n0 >> 4) + r_) * slabStride)                    \
                            + (size_t)(kk) * 16 + lane * 8;                                         \
        __builtin_amdgcn_global_load_lds((const __attribute__((address_space(1))) void*)src_,       \
            (__attribute__((address_space(3))) void*)&lds[(isA_ ? 0 : 16384) + (buf) * 8192 + r_ * 512], \
            16, 0, 0);                                                                              \
    } while (0)

    // prologue: full stage 0
    STAGE1(0, 0, 0); STAGE1(0, 0, 1); STAGE1(0, 0, 2); STAGE1(0, 0, 3);

#pragma unroll 2
    for (int t = 0; t < NT; ++t) {
        const int cur = t & 1;
        const unsigned aB = ldsBase + (unsigned)cur * 16384u;
        const unsigned bB = ldsBase + 32768u + (unsigned)cur * 16384u;
        s16x8 bv[4];

        // ---------- phase 0: vmcnt sync + all-B + A pair {0,1} + MFMA i=0,1
        if (t + 1 < NT) {
            STAGE1(cur ^ 1, (t + 1) * 32, 0);
            asm volatile("s_waitcnt vmcnt(1)" ::: "memory");   // stage t landed; newest stays in flight
        } else {
            asm volatile("s_waitcnt vmcnt(0)" ::: "memory");
        }
        __builtin_amdgcn_sched_barrier(0);
        __builtin_amdgcn_s_barrier();        // all waves' buf[cur] ready
        __builtin_amdgcn_sched_barrier(0);
        {
            s16x4 bl[4], bh[4], a0l, a0h, a1l, a1h;
#pragma unroll
            for (int j = 0; j < 4; ++j) {
                unsigned bd = bB + ((unsigned)(wn * 4 + j) << 10) + ((unsigned)lane << 3);
                asm volatile("ds_read_b64_tr_b16 %0, %1 offset:0"   : "=v"(bl[j]) : "v"(bd));
                asm volatile("ds_read_b64_tr_b16 %0, %1 offset:512" : "=v"(bh[j]) : "v"(bd));
            }
            unsigned ad0 = aB + ((unsigned)(wm * 8 + 0) << 10) + ((unsigned)lane << 3);
            unsigned ad1 = aB + ((unsigned)(wm * 8 + 1) << 10) + ((unsigned)lane << 3);
            asm volatile("ds_read_b64_tr_b16 %0, %1 offset:0"   : "=v"(a0l) : "v"(ad0));
            asm volatile("ds_read_b64_tr_b16 %0, %1 offset:512" : "=v"(a0h) : "v"(ad0));
            asm volatile("ds_read_b64_tr_b16 %0, %1 offset:0"   : "=v"(a1l) : "v"(ad1));
            asm volatile("ds_read_b64_tr_b16 %0, %1 offset:512" : "=v"(a1h) : "v"(ad1));
            asm volatile("s_waitcnt lgkmcnt(0)" ::: "memory");
            __builtin_amdgcn_sched_barrier(0);   // rule 18
#pragma unroll
            for (int j = 0; j < 4; ++j)
                bv[j] = __builtin_shufflevector(bl[j], bh[j], 0, 1, 2, 3, 4, 5, 6, 7);
            s16x8 a0 = __builtin_shufflevector(a0l, a0h, 0, 1, 2, 3, 4, 5, 6, 7);
            s16x8 a1 = __builtin_shufflevector(a1l, a1h, 0, 1, 2, 3, 4, 5, 6, 7);
            __builtin_amdgcn_s_setprio(1);
#pragma unroll
            for (int j = 0; j < 4; ++j) {
                acc[0][j] = __builtin_amdgcn_mfma_f32_16x16x32_bf16(a0, bv[j], acc[0][j], 0, 0, 0);
                acc[1][j] = __builtin_amdgcn_mfma_f32_16x16x32_bf16(a1, bv[j], acc[1][j], 0, 0, 0);
            }
            __builtin_amdgcn_s_setprio(0);
        }
        __builtin_amdgcn_s_barrier();        // phase boundary
        __builtin_amdgcn_sched_barrier(0);

        // ---------- phases 1..3: A pair {2p,2p+1} + MFMA i=2p,2p+1
#pragma unroll
        for (int p = 1; p < 4; ++p) {
            if (t + 1 < NT) STAGE1(cur ^ 1, (t + 1) * 32, p);
            s16x4 a0l, a0h, a1l, a1h;
            unsigned ad0 = aB + ((unsigned)(wm * 8 + 2 * p) << 10) + ((unsigned)lane << 3);
            unsigned ad1 = aB + ((unsigned)(wm * 8 + 2 * p + 1) << 10) + ((unsigned)lane << 3);
            asm volatile("ds_read_b64_tr_b16 %0, %1 offset:0"   : "=v"(a0l) : "v"(ad0));
            asm volatile("ds_read_b64_tr_b16 %0, %1 offset:512" : "=v"(a0h) : "v"(ad0));
            asm volatile("ds_read_b64_tr_b16 %0, %1 offset:0"   : "=v"(a1l) : "v"(ad1));
            asm volatile("ds_read_b64_tr_b16 %0, %1 offset:512" : "=v"(a1h) : "v"(ad1));
            asm volatile("s_waitcnt lgkmcnt(0)" ::: "memory");
            __builtin_amdgcn_sched_barrier(0);   // rule 18
            s16x8 a0 = __builtin_shufflevector(a0l, a0h, 0, 1, 2, 3, 4, 5, 6, 7);
            s16x8 a1 = __builtin_shufflevector(a1l, a1h, 0, 1, 2, 3, 4, 5, 6, 7);
            __builtin_amdgcn_s_setprio(1);
#pragma unroll
            for (int j = 0; j < 4; ++j) {
                acc[2 * p][j]     = __builtin_amdgcn_mfma_f32_16x16x32_bf16(a0, bv[j], acc[2 * p][j], 0, 0, 0);
                acc[2 * p + 1][j] = __builtin_amdgcn_mfma_f32_16x16x32_bf16(a1, bv[j], acc[2 * p + 1][j], 0, 0, 0);
            }
            __builtin_amdgcn_s_setprio(0);
            // phase-end barrier; at p==3 also the write-after-read guard:
            // all reads of buf[cur] are done (each wave's lgkmcnt(0) above)
            // before any wave issues next step's overwrite of buf[cur^1]...
            // (2-deep ring: stage t+1 overwrites the buffer read at t-1, whose
            // readers passed this barrier at step t-1).
            __builtin_amdgcn_s_barrier();
            __builtin_amdgcn_sched_barrier(0);
        }
    }
#undef STAGE1

    const int cn = lane & 15;
    const int g4 = (lane >> 4) * 4;
    if (!PACKOUT) {
        // C/D layout: col = lane&15, row = (lane>>4)*4 + reg  [m89]
#pragma unroll
        for (int i = 0; i < 8; ++i) {
            int mrow = m0 + wm * 128 + i * 16 + g4;
#pragma unroll
            for (int j = 0; j < 4; ++j) {
                int ncol = n0 + wn * 64 + j * 16 + cn;
                float* cp = Cf + (size_t)mrow * TWO_N + ncol;
#pragma unroll
                for (int r = 0; r < 4; ++r) {
                    float v = acc[i][j][r];
                    if (((mrow + r) & (TSTEPS - 1)) == 0)   // t==0 row: out = xi_init
                        v = xi0[((mrow + r) >> 11) * TWO_N + ncol];
                    cp[(size_t)r * TWO_N] = v;
                }
            }
        }
    } else {
        // direct packed-bf16 stores: slab = (m>>4), addr = slab*8192 + n*16 + (m&15)
#pragma unroll
        for (int i = 0; i < 8; ++i) {
            size_t slab = (size_t)((m0 >> 4) + wm * 8 + i);
#pragma unroll
            for (int j = 0; j < 4; ++j) {
                int n = n0 + wn * 64 + j * 16 + cn;
                s16x4 pv;
#pragma unroll
                for (int r = 0; r < 4; ++r) {
                    __hip_bfloat16 bb = __float2bfloat16(acc[i][j][r]);
                    pv[r] = *reinterpret_cast<short*>(&bb);
                }
                *reinterpret_cast<s16x4*>(Cp + slab * 8192 + (size_t)n * 16 + g4) = pv;
            }
        }
    }
}

// ---- vectorized chunked diagonal scan (packed layout: thread's data is contiguous) ----
__global__ __launch_bounds__(256) void scan_passA(const short* __restrict__ Fpk,
                                                  const float* __restrict__ dbuf,
                                                  float* __restrict__ e) {
    int b = blockIdx.x, c = blockIdx.y, i = threadIdx.x;   // i = complex state 0..255
    float dr = dbuf[i], di = dbuf[N_ST + i];
    float re = 0.f, im = 0.f;
    int slab0 = (b * TSTEPS + c * CHUNKL) >> 4;   // 4 slabs per chunk
#pragma unroll
    for (int g = 0; g < 4; ++g) {
        const short* base = Fpk + (size_t)(slab0 + g) * 8192 + i * 16;
        s16x8 r0 = *reinterpret_cast<const s16x8*>(base);
        s16x8 r1 = *reinterpret_cast<const s16x8*>(base + 8);
        s16x8 i0 = *reinterpret_cast<const s16x8*>(base + 4096);
        s16x8 i1 = *reinterpret_cast<const s16x8*>(base + 4096 + 8);
#pragma unroll
        for (int j = 0; j < 16; ++j) {
            float fr = bf2f(j < 8 ? r0[j & 7] : r1[j & 7]);
            float fi = bf2f(j < 8 ? i0[j & 7] : i1[j & 7]);
            float nre = fmaf(dr, re, fmaf(-di, im, fr));
            float nim = fmaf(dr, im, fmaf(di, re, fi));
            re = nre; im = nim;
        }
    }
    size_t o = ((size_t)(b * NCHUNK + c)) * TWO_N;
    e[o + i] = re;
    e[o + N_ST + i] = im;
}

// ---- scanC with integrated cross-chunk prefix (scanB folded in) ----
__global__ __launch_bounds__(256) void scan_passC(const short* __restrict__ Fpk,
                                                  const float* __restrict__ dbuf,
                                                  const float* __restrict__ e,
                                                  const float* __restrict__ xbar0,
                                                  short* __restrict__ Zpk) {
    int b = blockIdx.x, c = blockIdx.y, i = threadIdx.x;
    float dr = dbuf[i], di = dbuf[N_ST + i];
    float dLr = dbuf[2 * N_ST + i], dLi = dbuf[3 * N_ST + i];
    float re = xbar0[b * TWO_N + i], im = xbar0[b * TWO_N + N_ST + i];
    for (int cc = 0; cc < c; ++cc) {   // prefix over earlier chunks (uniform bound)
        size_t o = ((size_t)(b * NCHUNK + cc)) * TWO_N;
        float er = e[o + i], ei = e[o + N_ST + i];
        float nre = fmaf(dLr, re, fmaf(-dLi, im, er));
        float nim = fmaf(dLr, im, fmaf(dLi, re, ei));
        re = nre; im = nim;
    }
    int slab0 = (b * TSTEPS + c * CHUNKL) >> 4;
#pragma unroll
    for (int g = 0; g < 4; ++g) {
        const short* base = Fpk + (size_t)(slab0 + g) * 8192 + i * 16;
        s16x8 r0 = *reinterpret_cast<const s16x8*>(base);
        s16x8 r1 = *reinterpret_cast<const s16x8*>(base + 8);
        s16x8 i0 = *reinterpret_cast<const s16x8*>(base + 4096);
        s16x8 i1 = *reinterpret_cast<const s16x8*>(base + 4096 + 8);
        s16x8 zr0, zr1, zi0, zi1;
#pragma unroll
        for (int j = 0; j < 16; ++j) {
            float fr = bf2f(j < 8 ? r0[j & 7] : r1[j & 7]);
            float fi = bf2f(j < 8 ? i0[j & 7] : i1[j & 7]);
            float nre = fmaf(dr, re, fmaf(-di, im, fr));
            float nim = fmaf(dr, im, fmaf(di, re, fi));
            re = nre; im = nim;
            __hip_bfloat16 br = __float2bfloat16(re), bi = __float2bfloat16(im);
            if (j < 8) { zr0[j & 7] = *(short*)&br; zi0[j & 7] = *(short*)&bi; }
            else       { zr1[j & 7] = *(short*)&br; zi1[j & 7] = *(short*)&bi; }
        }
        short* zb = Zpk + (size_t)(slab0 + g) * 8192 + i * 16;
        *reinterpret_cast<s16x8*>(zb)            = zr0;
        *reinterpret_cast<s16x8*>(zb + 8)        = zr1;
        *reinterpret_cast<s16x8*>(zb + 4096)     = zi0;
        *reinterpret_cast<s16x8*>(zb + 4096 + 8) = zi1;
    }
}

extern "C" void kernel_launch(void* const* d_in, const int* in_sizes, int n_in,
                              void* d_out, int out_size, void* d_ws, size_t ws_size,
                              hipStream_t stream) {
    const float* xi_init = (const float*)d_in[0];
    const float* u_log   = (const float*)d_in[1];
    const float* alpha   = (const float*)d_in[2];
    const float* theta   = (const float*)d_in[3];
    const float* B_re    = (const float*)d_in[4];
    const float* B_im    = (const float*)d_in[5];
    const float* P_re    = (const float*)d_in[6];
    const float* P_im    = (const float*)d_in[7];
    const float* Pinv_re = (const float*)d_in[8];
    const float* Pinv_im = (const float*)d_in[9];
    float* out = (float*)d_out;
    float* ws  = (float*)d_ws;

    short* Fpk  = (short*)(ws + OFF_FPK);
    short* Zpk  = (short*)(ws + OFF_ZPK);
    short* upk  = (short*)(ws + OFF_UPK);
    short* Wtpk = (short*)(ws + OFF_WT);
    short* Wfpk = (short*)(ws + OFF_WF);
    float* dbuf  = ws + OFF_D;
    float* xbar0 = ws + OFF_XBAR0;
    float* e     = ws + OFF_E;

    prep_all<<<1281, 256, 0, stream>>>(P_re, P_im, B_re, B_im, alpha, theta,
                                       Wtpk, Wfpk, dbuf);
    xbar0_kernel<<<64, 256, 0, stream>>>(Pinv_re, Pinv_im, xi_init, xbar0);
    upack<<<MTOT / 64, 256, 0, stream>>>(u_log, upk);

    // forcing (packed bf16 out): F = h * u @ Bc^T   (256x256 tile, 8 waves)
    gemm_mfma<NU, true><<<256, 512, 0, stream>>>(
        upk, Wfpk, nullptr, Fpk, nullptr);

    // chunked diagonal scan (32 chunks of 64 steps); scanB folded into scanC
    scan_passA<<<dim3(BATCH, NCHUNK), 256, 0, stream>>>(Fpk, dbuf, e);
    scan_passC<<<dim3(BATCH, NCHUNK), 256, 0, stream>>>(Fpk, dbuf, e, xbar0, Zpk);

    // output projection: out = Z @ W^T (f32 out, t==0 rows = xi_init folded in epilogue)
    gemm_mfma<TWO_N, false><<<256, 512, 0, stream>>>(
        Zpk, Wtpk, out, nullptr, xi_init);
}

// Round 13
// 73.578 us; speedup vs baseline: 1.1140x; 1.1140x over previous
//
#include <hip/hip_runtime.h>
#include <hip/hip_bf16.h>
#include <cstddef>
#include <cstdint>

#define N_ST 256
#define TWO_N 512
#define NU 128
#define BATCH 16
#define TSTEPS 2048
#define MTOT (BATCH * TSTEPS)   // 32768
#define H_STEP 0.01f
#define EPS_V 0.001f
#define NCHUNK 32
#define CHUNKL 64

typedef __attribute__((ext_vector_type(4))) float f32x4;
typedef __attribute__((ext_vector_type(4))) short s16x4;
typedef __attribute__((ext_vector_type(8))) short s16x8;

// ---- workspace layout (float offsets) ----
#define OFF_FPK    0            // 16777216 shorts: packed bf16 F [(m>>4)][k=512][m&15]
#define OFF_ZPK    8388608      // 16777216 shorts: packed bf16 Z, same layout
#define OFF_UPK    16777216     // 4194304 shorts: packed bf16 u [(m>>4)][k=128][m&15]
#define OFF_WT     18874368     // 262144 shorts
#define OFF_WF     19005440     // 65536 shorts
#define OFF_D      19038208     // 1024 f32
#define OFF_XBAR0  19039232     // 8192 f32
#define OFF_E      19047424     // 512*512 f32

static __device__ __forceinline__ float bf2f(short s) {
    return __uint_as_float(((unsigned)(unsigned short)s) << 16);
}

// ---- merged precompute: blocks 0..1023 prep_W, 1024..1279 prep_Wf, 1280 prep_d,
// 1281..1344 xbar0 (64), 1345..1856 upack (512). One dispatch, fewer gaps.
__global__ __launch_bounds__(256) void prep_mega(
    const float* __restrict__ P_re, const float* __restrict__ P_im,
    const float* __restrict__ B_re, const float* __restrict__ B_im,
    const float* __restrict__ alpha, const float* __restrict__ theta,
    const float* __restrict__ Pinv_re, const float* __restrict__ Pinv_im,
    const float* __restrict__ xi0, const float* __restrict__ u,
    short* __restrict__ Wtpk, short* __restrict__ Wfpk,
    float* __restrict__ dbuf, float* __restrict__ xbar0,
    short* __restrict__ upk)
{
    __shared__ float xs[BATCH * TWO_N];   // 32 KB, reused as short* by upack branch
    int blk = blockIdx.x, tid = threadIdx.x;
    if (blk < 1024) {
        int idx = blk * 256 + tid;
        int j = idx >> 9, c = idx & 511;
        float v;
        if (c < N_ST) v = P_re[j * TWO_N + c] + P_re[j * TWO_N + c + N_ST];
        else          v = P_im[j * TWO_N + c] - P_im[j * TWO_N + c - N_ST];
        __hip_bfloat16 b = __float2bfloat16(v);
        Wtpk[((size_t)(j >> 4) * TWO_N + c) * 16 + (j & 15)] = *(short*)&b;
    } else if (blk < 1280) {
        int idx = (blk - 1024) * 256 + tid;
        int k = idx >> 9, c = idx & 511;
        float v = (c < N_ST) ? B_re[c * NU + k] : B_im[(c - N_ST) * NU + k];
        __hip_bfloat16 b = __float2bfloat16(H_STEP * v);
        Wfpk[((size_t)(c >> 4) * NU + k) * 16 + (c & 15)] = *(short*)&b;
    } else if (blk == 1280) {
        int i = tid;
        float dr = 1.0f + H_STEP * (-expf(alpha[i]) - EPS_V);
        float di = H_STEP * theta[i];
        float pr = 1.0f, pi = 0.0f;
        for (int k = 0; k < CHUNKL; ++k) { float nr = pr * dr - pi * di; pi = pr * di + pi * dr; pr = nr; }
        dbuf[i] = dr; dbuf[N_ST + i] = di; dbuf[2 * N_ST + i] = pr; dbuf[3 * N_ST + i] = pi;
    } else if (blk < 1345) {
        // xbar0: wave-per-state, coalesced Pinv reads, shfl reduce
#pragma unroll
        for (int q = 0; q < 8; ++q)
            *reinterpret_cast<float4*>(&xs[(q * 256 + tid) * 4]) =
                *reinterpret_cast<const float4*>(&xi0[(q * 256 + tid) * 4]);
        __syncthreads();
        int wv = tid >> 6, l = tid & 63;
        int i = (blk - 1281) * 4 + wv;    // state 0..255
        float rp[BATCH] = {}, ip[BATCH] = {};
#pragma unroll
        for (int q = 0; q < 8; ++q) {
            int j = q * 64 + l;
            float pr = Pinv_re[(size_t)i * TWO_N + j];
            float pi = Pinv_im[(size_t)i * TWO_N + j];
#pragma unroll
            for (int b = 0; b < BATCH; ++b) {
                float x = xs[b * TWO_N + j];
                rp[b] = fmaf(pr, x, rp[b]);
                ip[b] = fmaf(pi, x, ip[b]);
            }
        }
#pragma unroll
        for (int m = 1; m < 64; m <<= 1) {
#pragma unroll
            for (int b = 0; b < BATCH; ++b) {
                rp[b] += __shfl_xor(rp[b], m, 64);
                ip[b] += __shfl_xor(ip[b], m, 64);
            }
        }
        if (l == 0) {
#pragma unroll
            for (int b = 0; b < BATCH; ++b) {
                xbar0[b * TWO_N + i] = rp[b];
                xbar0[b * TWO_N + N_ST + i] = ip[b];
            }
        }
    } else {
        // upack: coalesced u -> packed bf16 via LDS transpose
        short* st = (short*)xs;           // 64*132 shorts = 16.9 KB < 32 KB
        int bid = blk - 1345;             // 0..511
        const float* up = u + (size_t)bid * 8192;
#pragma unroll
        for (int q = 0; q < 8; ++q) {
            int idx = q * 1024 + tid * 4;
            float4 v = *reinterpret_cast<const float4*>(up + idx);
            int m = idx >> 7, k = idx & 127;
            s16x4 pv;
            __hip_bfloat16 b0 = __float2bfloat16(v.x); pv[0] = *(short*)&b0;
            __hip_bfloat16 b1 = __float2bfloat16(v.y); pv[1] = *(short*)&b1;
            __hip_bfloat16 b2 = __float2bfloat16(v.z); pv[2] = *(short*)&b2;
            __hip_bfloat16 b3 = __float2bfloat16(v.w); pv[3] = *(short*)&b3;
            *reinterpret_cast<__shared__ s16x4*>(&st[m * 132 + k]) = pv;
        }
        __syncthreads();
        short* op = upk + (size_t)bid * 8192;
#pragma unroll
        for (int q2 = 0; q2 < 4; ++q2) {
            int o = q2 * 2048 + tid * 8;
            int ml = o & 15, k = (o >> 4) & 127, sl = o >> 11;
            s16x8 w;
#pragma unroll
            for (int r = 0; r < 8; ++r) w[r] = st[(sl * 16 + ml + r) * 132 + k];
            *reinterpret_cast<s16x8*>(op + o) = w;
        }
    }
}

// ---- bf16 MFMA GEMM, 256x256 tile, 8 waves, 3-deep buffer ring (depth-2
// prefetch), counted vmcnt (T4: N = 2 stages x 4 loads = 8), two raw barriers
// per K-step (round-9 race-free skeleton). 96 KB LDS, 1 block/CU (grid=256).
template <int K, bool PACKOUT>
__global__ __launch_bounds__(512, 2) void gemm_mfma(const short* __restrict__ Apk,
                                                    const short* __restrict__ Bpk,
                                                    float* __restrict__ Cf,
                                                    short* __restrict__ Cp,
                                                    const float* __restrict__ xi0) {
    __shared__ __align__(1024) short lds[49152];   // A: buf*8192 (3 bufs), B: 24576 + buf*8192
    const int tid = threadIdx.x;
    const int wid = tid >> 6, lane = tid & 63;
    const int l = blockIdx.x;
    const int mb = ((l >> 4) << 3) | (l & 7);      // XCD-pairing swizzle
    const int nb = (l >> 3) & 1;
    const int m0 = mb * 256, n0 = nb * 256;
    const int wm = wid >> 2, wn = wid & 3;         // 2 x 4 wave grid; wave tile 128x64
    f32x4 acc[8][4] = {};
    const size_t slabStride = (size_t)K * 16;
    const unsigned ldsBase = (unsigned)(uintptr_t)(__attribute__((address_space(3))) short*)&lds[0];
    constexpr int NT = K / 32;

#define STAGE(buf, kk)                                                                              \
    do {                                                                                            \
        const short* gA0 = Apk + ((size_t)(m0 >> 4) + wid)     * slabStride + (size_t)(kk) * 16 + lane * 8; \
        const short* gA1 = Apk + ((size_t)(m0 >> 4) + wid + 8) * slabStride + (size_t)(kk) * 16 + lane * 8; \
        const short* gB0 = Bpk + ((size_t)(n0 >> 4) + wid)     * slabStride + (size_t)(kk) * 16 + lane * 8; \
        const short* gB1 = Bpk + ((size_t)(n0 >> 4) + wid + 8) * slabStride + (size_t)(kk) * 16 + lane * 8; \
        __builtin_amdgcn_global_load_lds((const __attribute__((address_space(1))) void*)gA0,        \
            (__attribute__((address_space(3))) void*)&lds[(buf) * 8192 + wid * 512], 16, 0, 0);     \
        __builtin_amdgcn_global_load_lds((const __attribute__((address_space(1))) void*)gA1,        \
            (__attribute__((address_space(3))) void*)&lds[(buf) * 8192 + (wid + 8) * 512], 16, 0, 0); \
        __builtin_amdgcn_global_load_lds((const __attribute__((address_space(1))) void*)gB0,        \
            (__attribute__((address_space(3))) void*)&lds[24576 + (buf) * 8192 + wid * 512], 16, 0, 0); \
        __builtin_amdgcn_global_load_lds((const __attribute__((address_space(1))) void*)gB1,        \
            (__attribute__((address_space(3))) void*)&lds[24576 + (buf) * 8192 + (wid + 8) * 512], 16, 0, 0); \
    } while (0)

    STAGE(0, 0);
    STAGE(1, 32);

#pragma unroll
    for (int t = 0; t < NT; ++t) {
        const int cur = t % 3;
        if (t + 2 < NT) STAGE((t + 2) % 3, (t + 2) * 32);   // keep 2 stages in flight
        // safe: buf[(t+2)%3]'s readers (iter t-1) passed barrier-2 of iter t-1

        // counted wait: stage t landed; stages t+1, t+2 stay in flight
        if (t + 2 < NT)      asm volatile("s_waitcnt vmcnt(8)" ::: "memory");
        else if (t + 1 < NT) asm volatile("s_waitcnt vmcnt(4)" ::: "memory");
        else                 asm volatile("s_waitcnt vmcnt(0)" ::: "memory");
        __builtin_amdgcn_sched_barrier(0);
        __builtin_amdgcn_s_barrier();        // barrier 1: all waves' buf[cur] loads complete
        __builtin_amdgcn_sched_barrier(0);

        s16x4 al[8], ah[8], bl[4], bh[4];
        const unsigned aB = ldsBase + (unsigned)cur * 16384u;
        const unsigned bB = ldsBase + 49152u + (unsigned)cur * 16384u;
#pragma unroll
        for (int i = 0; i < 8; ++i) {
            unsigned ad = aB + ((unsigned)(wm * 8 + i) << 10) + ((unsigned)lane << 3);
            asm volatile("ds_read_b64_tr_b16 %0, %1 offset:0"   : "=v"(al[i]) : "v"(ad));
            asm volatile("ds_read_b64_tr_b16 %0, %1 offset:512" : "=v"(ah[i]) : "v"(ad));
        }
#pragma unroll
        for (int j = 0; j < 4; ++j) {
            unsigned bd = bB + ((unsigned)(wn * 4 + j) << 10) + ((unsigned)lane << 3);
            asm volatile("ds_read_b64_tr_b16 %0, %1 offset:0"   : "=v"(bl[j]) : "v"(bd));
            asm volatile("ds_read_b64_tr_b16 %0, %1 offset:512" : "=v"(bh[j]) : "v"(bd));
        }
        asm volatile("s_waitcnt lgkmcnt(0)" ::: "memory");
        __builtin_amdgcn_sched_barrier(0);   // rule 18: no MFMA hoisting above the wait
        __builtin_amdgcn_s_barrier();        // barrier 2: all waves done reading buf[cur]
        __builtin_amdgcn_sched_barrier(0);

        __builtin_amdgcn_s_setprio(1);
#pragma unroll
        for (int i = 0; i < 8; ++i) {
            s16x8 av = __builtin_shufflevector(al[i], ah[i], 0, 1, 2, 3, 4, 5, 6, 7);
#pragma unroll
            for (int j = 0; j < 4; ++j) {
                s16x8 bv = __builtin_shufflevector(bl[j], bh[j], 0, 1, 2, 3, 4, 5, 6, 7);
                acc[i][j] = __builtin_amdgcn_mfma_f32_16x16x32_bf16(av, bv, acc[i][j], 0, 0, 0);
            }
        }
        __builtin_amdgcn_s_setprio(0);
    }
#undef STAGE

    const int cn = lane & 15;
    const int g4 = (lane >> 4) * 4;
    if (!PACKOUT) {
        // C/D layout: col = lane&15, row = (lane>>4)*4 + reg  [m89]
#pragma unroll
        for (int i = 0; i < 8; ++i) {
            int mrow = m0 + wm * 128 + i * 16 + g4;
#pragma unroll
            for (int j = 0; j < 4; ++j) {
                int ncol = n0 + wn * 64 + j * 16 + cn;
                float* cp = Cf + (size_t)mrow * TWO_N + ncol;
#pragma unroll
                for (int r = 0; r < 4; ++r) {
                    float v = acc[i][j][r];
                    if (((mrow + r) & (TSTEPS - 1)) == 0)   // t==0 row: out = xi_init
                        v = xi0[((mrow + r) >> 11) * TWO_N + ncol];
                    cp[(size_t)r * TWO_N] = v;
                }
            }
        }
    } else {
        // direct packed-bf16 stores: slab = (m>>4), addr = slab*8192 + n*16 + (m&15)
#pragma unroll
        for (int i = 0; i < 8; ++i) {
            size_t slab = (size_t)((m0 >> 4) + wm * 8 + i);
#pragma unroll
            for (int j = 0; j < 4; ++j) {
                int n = n0 + wn * 64 + j * 16 + cn;
                s16x4 pv;
#pragma unroll
                for (int r = 0; r < 4; ++r) {
                    __hip_bfloat16 bb = __float2bfloat16(acc[i][j][r]);
                    pv[r] = *reinterpret_cast<short*>(&bb);
                }
                *reinterpret_cast<s16x4*>(Cp + slab * 8192 + (size_t)n * 16 + g4) = pv;
            }
        }
    }
}

// ---- vectorized chunked diagonal scan (packed layout: thread's data is contiguous) ----
__global__ __launch_bounds__(256) void scan_passA(const short* __restrict__ Fpk,
                                                  const float* __restrict__ dbuf,
                                                  float* __restrict__ e) {
    int b = blockIdx.x, c = blockIdx.y, i = threadIdx.x;   // i = complex state 0..255
    float dr = dbuf[i], di = dbuf[N_ST + i];
    float re = 0.f, im = 0.f;
    int slab0 = (b * TSTEPS + c * CHUNKL) >> 4;   // 4 slabs per chunk
#pragma unroll
    for (int g = 0; g < 4; ++g) {
        const short* base = Fpk + (size_t)(slab0 + g) * 8192 + i * 16;
        s16x8 r0 = *reinterpret_cast<const s16x8*>(base);
        s16x8 r1 = *reinterpret_cast<const s16x8*>(base + 8);
        s16x8 i0 = *reinterpret_cast<const s16x8*>(base + 4096);
        s16x8 i1 = *reinterpret_cast<const s16x8*>(base + 4096 + 8);
#pragma unroll
        for (int j = 0; j < 16; ++j) {
            float fr = bf2f(j < 8 ? r0[j & 7] : r1[j & 7]);
            float fi = bf2f(j < 8 ? i0[j & 7] : i1[j & 7]);
            float nre = fmaf(dr, re, fmaf(-di, im, fr));
            float nim = fmaf(dr, im, fmaf(di, re, fi));
            re = nre; im = nim;
        }
    }
    size_t o = ((size_t)(b * NCHUNK + c)) * TWO_N;
    e[o + i] = re;
    e[o + N_ST + i] = im;
}

// ---- scanC with integrated cross-chunk prefix (scanB folded in) ----
__global__ __launch_bounds__(256) void scan_passC(const short* __restrict__ Fpk,
                                                  const float* __restrict__ dbuf,
                                                  const float* __restrict__ e,
                                                  const float* __restrict__ xbar0,
                                                  short* __restrict__ Zpk) {
    int b = blockIdx.x, c = blockIdx.y, i = threadIdx.x;
    float dr = dbuf[i], di = dbuf[N_ST + i];
    float dLr = dbuf[2 * N_ST + i], dLi = dbuf[3 * N_ST + i];
    float re = xbar0[b * TWO_N + i], im = xbar0[b * TWO_N + N_ST + i];
    for (int cc = 0; cc < c; ++cc) {   // prefix over earlier chunks (uniform bound)
        size_t o = ((size_t)(b * NCHUNK + cc)) * TWO_N;
        float er = e[o + i], ei = e[o + N_ST + i];
        float nre = fmaf(dLr, re, fmaf(-dLi, im, er));
        float nim = fmaf(dLr, im, fmaf(dLi, re, ei));
        re = nre; im = nim;
    }
    int slab0 = (b * TSTEPS + c * CHUNKL) >> 4;
#pragma unroll
    for (int g = 0; g < 4; ++g) {
        const short* base = Fpk + (size_t)(slab0 + g) * 8192 + i * 16;
        s16x8 r0 = *reinterpret_cast<const s16x8*>(base);
        s16x8 r1 = *reinterpret_cast<const s16x8*>(base + 8);
        s16x8 i0 = *reinterpret_cast<const s16x8*>(base + 4096);
        s16x8 i1 = *reinterpret_cast<const s16x8*>(base + 4096 + 8);
        s16x8 zr0, zr1, zi0, zi1;
#pragma unroll
        for (int j = 0; j < 16; ++j) {
            float fr = bf2f(j < 8 ? r0[j & 7] : r1[j & 7]);
            float fi = bf2f(j < 8 ? i0[j & 7] : i1[j & 7]);
            float nre = fmaf(dr, re, fmaf(-di, im, fr));
            float nim = fmaf(dr, im, fmaf(di, re, fi));
            re = nre; im = nim;
            __hip_bfloat16 br = __float2bfloat16(re), bi = __float2bfloat16(im);
            if (j < 8) { zr0[j & 7] = *(short*)&br; zi0[j & 7] = *(short*)&bi; }
            else       { zr1[j & 7] = *(short*)&br; zi1[j & 7] = *(short*)&bi; }
        }
        short* zb = Zpk + (size_t)(slab0 + g) * 8192 + i * 16;
        *reinterpret_cast<s16x8*>(zb)            = zr0;
        *reinterpret_cast<s16x8*>(zb + 8)        = zr1;
        *reinterpret_cast<s16x8*>(zb + 4096)     = zi0;
        *reinterpret_cast<s16x8*>(zb + 4096 + 8) = zi1;
    }
}

extern "C" void kernel_launch(void* const* d_in, const int* in_sizes, int n_in,
                              void* d_out, int out_size, void* d_ws, size_t ws_size,
                              hipStream_t stream) {
    const float* xi_init = (const float*)d_in[0];
    const float* u_log   = (const float*)d_in[1];
    const float* alpha   = (const float*)d_in[2];
    const float* theta   = (const float*)d_in[3];
    const float* B_re    = (const float*)d_in[4];
    const float* B_im    = (const float*)d_in[5];
    const float* P_re    = (const float*)d_in[6];
    const float* P_im    = (const float*)d_in[7];
    const float* Pinv_re = (const float*)d_in[8];
    const float* Pinv_im = (const float*)d_in[9];
    float* out = (float*)d_out;
    float* ws  = (float*)d_ws;

    short* Fpk  = (short*)(ws + OFF_FPK);
    short* Zpk  = (short*)(ws + OFF_ZPK);
    short* upk  = (short*)(ws + OFF_UPK);
    short* Wtpk = (short*)(ws + OFF_WT);
    short* Wfpk = (short*)(ws + OFF_WF);
    float* dbuf  = ws + OFF_D;
    float* xbar0 = ws + OFF_XBAR0;
    float* e     = ws + OFF_E;

    // all precompute + packing in one dispatch (fewer gaps, straggler overlap)
    prep_mega<<<1857, 256, 0, stream>>>(P_re, P_im, B_re, B_im, alpha, theta,
                                        Pinv_re, Pinv_im, xi_init, u_log,
                                        Wtpk, Wfpk, dbuf, xbar0, upk);

    // forcing (packed bf16 out): F = h * u @ Bc^T   (256x256 tile, 3-deep ring)
    gemm_mfma<NU, true><<<256, 512, 0, stream>>>(
        upk, Wfpk, nullptr, Fpk, nullptr);

    // chunked diagonal scan (32 chunks of 64 steps); scanB folded into scanC
    scan_passA<<<dim3(BATCH, NCHUNK), 256, 0, stream>>>(Fpk, dbuf, e);
    scan_passC<<<dim3(BATCH, NCHUNK), 256, 0, stream>>>(Fpk, dbuf, e, xbar0, Zpk);

    // output projection: out = Z @ W^T (f32 out, t==0 rows = xi_init folded in epilogue)
    gemm_mfma<TWO_N, false><<<256, 512, 0, stream>>>(
        Zpk, Wtpk, out, nullptr, xi_init);
}